// Round 6
// baseline (308.008 us; speedup 1.0000x reference)
//
#include <hip/hip_runtime.h>

#define CC    192
#define EXT   64
#define LDC   200         // bf16 row stride (400 B): 16B-aligned b128 frags, ~2-way banks
#define NTH   512         // 8 waves
#define HALO  13
#define INTR  38
#define TT    8192
#define BATCH 16
#define NTILES 216        // ceil(8192/38)
#define NPROJ 29

#define WQ1_ELEMS (3*6*12*512)   // 110592
#define WQ2_ELEMS (6*2*512)      // 6144

typedef __bf16 bf16x8 __attribute__((ext_vector_type(8)));
typedef __bf16 bf16x4 __attribute__((ext_vector_type(4)));
typedef __bf16 bf16x2 __attribute__((ext_vector_type(2)));
typedef float  f32x4  __attribute__((ext_vector_type(4)));

// gelu via tanh-approx: gelu(v) = v * sigmoid(1.59577 v + 0.0713548 v^3)
__device__ __forceinline__ float gelu_fast(float v) {
    float vv = v * v;
    float u2 = v * fmaf(0.0713548162f, vv, 1.5957691216f);
    float t  = __expf(u2);
    float r  = __builtin_amdgcn_rcpf(t + 1.0f);
    return v - v * r;
}
__device__ __forceinline__ float softplus_f(float v) {
    float e = __expf(-fabsf(v));
    return fmaxf(v, 0.0f) + __logf(1.0f + e);
}

// Prepack pw_w (3x192x192) + w_proj (29x192 -> 32 rows) into MFMA A-frag bf16.
__global__ __launch_bounds__(256) void prepack_kernel(
    const float* __restrict__ pw_w, const float* __restrict__ w_proj,
    __bf16* __restrict__ wq, __bf16* __restrict__ wq2) {
    int idx = blockIdx.x * 256 + threadIdx.x;
    if (idx < WQ1_ELEMS) {
        int e    = idx & 7;
        int lane = (idx >> 3) & 63;
        int r    = idx >> 9;
        int mt   = r % 12;
        int ks   = (r / 12) % 6;
        int li   = r / 72;
        int o = 16 * mt + (lane & 15);
        int c = 32 * ks + 8 * (lane >> 4) + e;
        wq[idx] = (__bf16)pw_w[((size_t)li * CC + o) * CC + c];
    } else if (idx < WQ1_ELEMS + WQ2_ELEMS) {
        int i2   = idx - WQ1_ELEMS;
        int e    = i2 & 7;
        int lane = (i2 >> 3) & 63;
        int r    = i2 >> 9;          // 0..11  = ks*2 + pr
        int pr   = r % 2;
        int ks   = r / 2;
        int row  = 16 * pr + (lane & 15);
        int c    = 32 * ks + 8 * (lane >> 4) + e;
        wq2[i2] = (row < NPROJ) ? (__bf16)w_proj[(size_t)row * CC + c] : (__bf16)0.0f;
    }
}

__global__ __launch_bounds__(NTH, 6) void convflow_kernel(
    const float* __restrict__ x, const float* __restrict__ xmask,
    const float* __restrict__ w_pre, const float* __restrict__ b_pre,
    const float* __restrict__ sep_w, const float* __restrict__ sep_b,
    const __bf16* __restrict__ wq, const __bf16* __restrict__ wq2,
    const float* __restrict__ pw_b,
    const float* __restrict__ n1_g, const float* __restrict__ n1_b,
    const float* __restrict__ n2_g, const float* __restrict__ n2_b,
    const float* __restrict__ b_proj,
    float* __restrict__ out, float* __restrict__ logdet)
{
    extern __shared__ char smemraw[];
    __bf16* __restrict__ sh_t = (__bf16*)smemraw;          // [64][200] masked residual h
    __bf16* __restrict__ syt  = sh_t + EXT * LDC;          // [64][200] LN1/gelu out
    float*  __restrict__ sproj = (float*)syt;              // alias: [64][33]
    __bf16* __restrict__ spb  = syt + EXT * LDC;           // [192] bf16 per-layer params
    __bf16* __restrict__ sg2  = spb + CC;                  // [192]
    __bf16* __restrict__ sb2  = sg2 + CC;                  // [192]
    float*  __restrict__ fbase = (float*)(sb2 + CC);
    float*  __restrict__ sx0 = fbase;                      // [64]
    float*  __restrict__ sx1 = fbase + 64;
    float*  __restrict__ smk = fbase + 128;
    float2* __restrict__ sred = (float2*)(fbase + 192);    // [64][2]

    const int tid  = threadIdx.x;
    const int lane = tid & 63;
    const int wav  = tid >> 6;          // 0..7
    const int b    = blockIdx.x / NTILES;
    const int tile = blockIdx.x - b * NTILES;
    const int t0   = tile * INTR - HALO;

    // ---- stage 0: inputs ----
    for (int j = tid; j < EXT; j += NTH) {
        int t = t0 + j;
        bool ok = (t >= 0) && (t < TT);
        sx0[j] = ok ? x[b*2*TT + t]      : 0.0f;
        sx1[j] = ok ? x[b*2*TT + TT + t] : 0.0f;
        smk[j] = ok ? xmask[b*TT + t]    : 0.0f;
    }
    __syncthreads();

    // ---- pre-projection (masked, transposed bf16) + x0 output copy ----
    for (int e = tid; e < CC*EXT; e += NTH) {
        int c = e % CC;
        int j = e / CC;
        sh_t[j*LDC + c] = (__bf16)((sx0[j] * w_pre[c] + b_pre[c]) * smk[j]);
    }
    for (int q = tid; q < INTR; q += NTH) {
        int t = t0 + HALO + q;
        if (t < TT) out[b*2*TT + t] = sx0[HALO+q] * smk[HALO+q];
    }
    __syncthreads();

    const int g   = lane >> 4;
    const int c15 = lane & 15;
    const int cl  = lane & 31;          // conv: channels 6cl..6cl+5
    const int sub = lane >> 5;          // conv column selector (0/1)
    const int nt   = wav & 3;           // pointwise N-tile
    const int half = wav >> 2;          // pointwise M-half

    #pragma unroll
    for (int li = 0; li < 3; ++li) {
        constexpr int DILA[3] = {1, 3, 9};
        constexpr int JLOA[3] = {1, 4, 13};
        constexpr int JHIA[3] = {63, 60, 51};
        const int dil = DILA[li];
        const int jlo = JLOA[li], jhi = JHIA[li];

        // ---- stage per-layer params into LDS (bf16) ----
        for (int i = tid; i < CC; i += NTH) {
            spb[i] = (__bf16)pw_b[li*CC + i];
            sg2[i] = (__bf16)n2_g[li*CC + i];
            sb2[i] = (__bf16)n2_b[li*CC + i];
        }

        // ---- depthwise conv + LN1 + gelu -> syt (32 lanes x 2 cols, 6 ch/lane) ----
        {
            float k0[6], k1[6], k2[6], cb[6], g1[6], b1[6];
            #pragma unroll
            for (int k = 0; k < 6; ++k) {
                int c = 6*cl + k;
                k0[k] = sep_w[(li*3+0)*CC + c];
                k1[k] = sep_w[(li*3+1)*CC + c];
                k2[k] = sep_w[(li*3+2)*CC + c];
                cb[k] = sep_b[li*CC + c];
                g1[k] = n1_g[li*CC + c];
                b1[k] = n1_b[li*CC + c];
            }
            for (int j = jlo + 2*wav + sub; j < jhi; j += 16) {
                const bf16x2* r0 = (const bf16x2*)(sh_t + (j-dil)*LDC + 6*cl);
                const bf16x2* r1 = (const bf16x2*)(sh_t + j*LDC       + 6*cl);
                const bf16x2* r2 = (const bf16x2*)(sh_t + (j+dil)*LDC + 6*cl);
                bf16x2 t0v[3], t1v[3], t2v[3];
                #pragma unroll
                for (int p = 0; p < 3; ++p) { t0v[p] = r0[p]; t1v[p] = r1[p]; t2v[p] = r2[p]; }
                float a[6]; float s = 0.0f, ss = 0.0f;
                #pragma unroll
                for (int k = 0; k < 6; ++k) {
                    float v = k0[k]*(float)t0v[k>>1][k&1]
                            + k1[k]*(float)t1v[k>>1][k&1]
                            + k2[k]*(float)t2v[k>>1][k&1] + cb[k];
                    a[k] = v; s += v; ss += v*v;
                }
                #pragma unroll
                for (int mm = 1; mm < 32; mm <<= 1) {
                    s  += __shfl_xor(s,  mm, 64);
                    ss += __shfl_xor(ss, mm, 64);
                }
                float mean = s * (1.0f/CC);
                float var  = ss * (1.0f/CC) - mean*mean;
                float rstd = rsqrtf(var + 1e-5f);
                #pragma unroll
                for (int p = 0; p < 3; ++p) {
                    bf16x2 w;
                    w[0] = (__bf16)gelu_fast((a[2*p+0]-mean)*rstd*g1[2*p+0] + b1[2*p+0]);
                    w[1] = (__bf16)gelu_fast((a[2*p+1]-mean)*rstd*g1[2*p+1] + b1[2*p+1]);
                    *(bf16x2*)(syt + j*LDC + 6*cl + 2*p) = w;
                }
            }
        }
        __syncthreads();

        // ---- pointwise 192x192 MFMA: 8 jobs = (nt 0..3) x (M-half 0..1) ----
        {
            f32x4 acc[6];
            #pragma unroll
            for (int q = 0; q < 6; ++q) {
                bf16x4 pb = *(const bf16x4*)(spb + 16*(6*half+q) + 4*g);
                acc[q][0] = (float)pb[0]; acc[q][1] = (float)pb[1];
                acc[q][2] = (float)pb[2]; acc[q][3] = (float)pb[3];
            }
            const __bf16* wql = wq + (size_t)li * (6*12*512);
            #pragma unroll
            for (int ks = 0; ks < 6; ++ks) {
                bf16x8 bfrag = *(const bf16x8*)(syt + (16*nt + c15)*LDC + 32*ks + 8*g);
                const __bf16* ap = wql + (size_t)(ks*12 + 6*half)*512 + lane*8;
                #pragma unroll
                for (int q = 0; q < 6; ++q) {
                    bf16x8 afrag = *(const bf16x8*)(ap + (size_t)q*512);
                    acc[q] = __builtin_amdgcn_mfma_f32_16x16x32_bf16(afrag, bfrag, acc[q], 0, 0, 0);
                }
            }
            // partial LN2 stats over this half's 96 channels
            float s = 0.0f, ss = 0.0f;
            #pragma unroll
            for (int q = 0; q < 6; ++q) {
                #pragma unroll
                for (int e = 0; e < 4; ++e) { float z = acc[q][e]; s += z; ss += z*z; }
            }
            s  += __shfl_xor(s, 16, 64);  s  += __shfl_xor(s, 32, 64);
            ss += __shfl_xor(ss, 16, 64); ss += __shfl_xor(ss, 32, 64);
            if (lane < 16) sred[(16*nt + lane)*2 + half] = make_float2(s, ss);
            __syncthreads();
            const int col = 16*nt + c15;
            float2 e0 = sred[col*2], e1 = sred[col*2+1];
            float mean = (e0.x + e1.x) * (1.0f/CC);
            float var  = (e0.y + e1.y) * (1.0f/CC) - mean*mean;
            float rstd = rsqrtf(var + 1e-5f);
            float mj   = smk[col];
            #pragma unroll
            for (int q = 0; q < 6; ++q) {
                int mt = 6*half + q;
                bf16x4 gv = *(const bf16x4*)(sg2 + 16*mt + 4*g);
                bf16x4 bv = *(const bf16x4*)(sb2 + 16*mt + 4*g);
                bf16x4 hv = *(bf16x4*)(sh_t + (size_t)col*LDC + 16*mt + 4*g);
                hv[0] = (__bf16)((float)hv[0] + gelu_fast((acc[q][0]-mean)*rstd*(float)gv[0] + (float)bv[0])*mj);
                hv[1] = (__bf16)((float)hv[1] + gelu_fast((acc[q][1]-mean)*rstd*(float)gv[1] + (float)bv[1])*mj);
                hv[2] = (__bf16)((float)hv[2] + gelu_fast((acc[q][2]-mean)*rstd*(float)gv[2] + (float)bv[2])*mj);
                hv[3] = (__bf16)((float)hv[3] + gelu_fast((acc[q][3]-mean)*rstd*(float)gv[3] + (float)bv[3])*mj);
                *(bf16x4*)(sh_t + (size_t)col*LDC + 16*mt + 4*g) = hv;
            }
        }
        __syncthreads();
    }

    // ---- final projection: 8 jobs = (nt 0..3) x (row-half 0..1) ----
    {
        const int pr = half;
        f32x4 p0 = {0,0,0,0};
        #pragma unroll
        for (int ks = 0; ks < 6; ++ks) {
            bf16x8 bfrag = *(const bf16x8*)(sh_t + (16*nt + c15)*LDC + 32*ks + 8*g);
            bf16x8 a0 = *(const bf16x8*)(wq2 + (size_t)(ks*2 + pr)*512 + lane*8);
            p0 = __builtin_amdgcn_mfma_f32_16x16x32_bf16(a0, bfrag, p0, 0, 0, 0);
        }
        const int col = 16*nt + c15;
        if (col >= HALO && col < HALO + INTR) {
            float mj = smk[col];
            #pragma unroll
            for (int e = 0; e < 4; ++e) {
                int p = 16*pr + 4*g + e;
                if (p < NPROJ) sproj[col*33 + p] = (p0[e] + b_proj[p])*mj;
            }
        }
    }
    __syncthreads();

    // ---- rational-quadratic spline (wave 0) ----
    if (tid < 64) {
        int j = HALO + tid;
        int t = t0 + j;
        float ladm = 0.0f;
        if (tid < INTR && t < TT) {
            const float SCALE = 0.07216878364870323f;  // 1/sqrt(192)
            float mj = smk[j];
            float uw[10], uh[10];
            #pragma unroll
            for (int k = 0; k < 10; ++k) {
                uw[k] = sproj[j*33 + k]      * SCALE;
                uh[k] = sproj[j*33 + 10 + k] * SCALE;
            }
            float mxw = uw[0];
            #pragma unroll
            for (int k = 1; k < 10; ++k) mxw = fmaxf(mxw, uw[k]);
            float ew[10]; float sew = 0.0f;
            #pragma unroll
            for (int k = 0; k < 10; ++k) { ew[k] = __expf(uw[k]-mxw); sew += ew[k]; }
            float invw = 1.0f/sew;
            float cw[11]; cw[0] = -5.0f;
            float run = 0.0f;
            #pragma unroll
            for (int k = 0; k < 10; ++k) { run += 0.001f + 0.99f*ew[k]*invw; cw[k+1] = -5.0f + 10.0f*run; }
            cw[10] = 5.0f;
            float mxh = uh[0];
            #pragma unroll
            for (int k = 1; k < 10; ++k) mxh = fmaxf(mxh, uh[k]);
            float eh[10]; float seh = 0.0f;
            #pragma unroll
            for (int k = 0; k < 10; ++k) { eh[k] = __expf(uh[k]-mxh); seh += eh[k]; }
            float invh = 1.0f/seh;
            float ch[11]; ch[0] = -5.0f;
            run = 0.0f;
            #pragma unroll
            for (int k = 0; k < 10; ++k) { run += 0.001f + 0.99f*eh[k]*invh; ch[k+1] = -5.0f + 10.0f*run; }
            ch[10] = 5.0f;
            float dd[11];
            dd[0] = 1.0f;
            #pragma unroll
            for (int k = 0; k < 9; ++k) dd[k+1] = 0.001f + softplus_f(sproj[j*33 + 20 + k]);
            dd[10] = 1.0f;

            float xv = sx1[j];
            bool inside = (xv >= -5.0f) && (xv <= 5.0f);
            float xi = fminf(fmaxf(xv, -5.0f), 5.0f);
            int idx = 0;
            #pragma unroll
            for (int k = 1; k <= 9; ++k) idx = (xi >= cw[k]) ? k : idx;
            float in_cw=0, in_w=1, in_ch=0, in_h=1, in_d=1, d_p=1;
            #pragma unroll
            for (int k = 0; k < 10; ++k) {
                if (k == idx) {
                    in_cw = cw[k]; in_w = cw[k+1]-cw[k];
                    in_ch = ch[k]; in_h = ch[k+1]-ch[k];
                    in_d  = dd[k]; d_p  = dd[k+1];
                }
            }
            float delta = in_h/in_w;
            float th  = (xi - in_cw)/in_w;
            float th1 = th*(1.0f-th);
            float num = in_h*(delta*th*th + in_d*th1);
            float den = delta + (in_d + d_p - 2.0f*delta)*th1;
            float yv  = in_ch + num/den;
            float omt = 1.0f - th;
            float dnum = delta*delta*(d_p*th*th + 2.0f*delta*th1 + in_d*omt*omt);
            float lad = __logf(dnum) - 2.0f*__logf(den);
            if (!inside) { yv = xv; lad = 0.0f; }
            out[b*2*TT + TT + t] = yv*mj;
            ladm = lad*mj;
        }
        #pragma unroll
        for (int mm = 1; mm < 64; mm <<= 1) ladm += __shfl_xor(ladm, mm, 64);
        if (tid == 0) atomicAdd(&logdet[b], ladm);
    }
}

extern "C" void kernel_launch(void* const* d_in, const int* in_sizes, int n_in,
                              void* d_out, int out_size, void* d_ws, size_t ws_size,
                              hipStream_t stream) {
    const float* x      = (const float*)d_in[0];
    const float* xmask  = (const float*)d_in[1];
    const float* w_pre  = (const float*)d_in[2];
    const float* b_pre  = (const float*)d_in[3];
    const float* sep_w  = (const float*)d_in[4];
    const float* sep_b  = (const float*)d_in[5];
    const float* pw_w   = (const float*)d_in[6];
    const float* pw_b   = (const float*)d_in[7];
    const float* n1_g   = (const float*)d_in[8];
    const float* n1_b   = (const float*)d_in[9];
    const float* n2_g   = (const float*)d_in[10];
    const float* n2_b   = (const float*)d_in[11];
    const float* w_proj = (const float*)d_in[12];
    const float* b_proj = (const float*)d_in[13];
    float* out = (float*)d_out;
    float* logdet = out + (size_t)BATCH*2*TT;
    __bf16* wq  = (__bf16*)d_ws;
    __bf16* wq2 = wq + WQ1_ELEMS;

    hipMemsetAsync((void*)logdet, 0, BATCH*sizeof(float), stream);
    prepack_kernel<<<dim3((WQ1_ELEMS + WQ2_ELEMS + 255)/256), 256, 0, stream>>>(
        pw_w, w_proj, wq, wq2);

    // 51200 (2 planes) + 1152 (bf16 params) + 768 (sx) + 1024 (sred) = 54144 B
    size_t shbytes = (size_t)(2*EXT*LDC*2 + 3*CC*2 + 192*4 + 64*2*8);
    dim3 grid(BATCH*NTILES);
    convflow_kernel<<<grid, NTH, shbytes, stream>>>(
        x, xmask, w_pre, b_pre, sep_w, sep_b, wq, wq2, pw_b,
        n1_g, n1_b, n2_g, n2_b, b_proj, out, logdet);
}

// Round 7
// 257.403 us; speedup vs baseline: 1.1966x; 1.1966x over previous
//
#include <hip/hip_runtime.h>

#define CC    192
#define EXT   64
#define LDC   200         // bf16 row stride (400 B): 16B-aligned b128 frags, ~2-way banks
#define NTH   512         // 8 waves
#define HALO  13
#define INTR  38
#define TT    8192
#define BATCH 16
#define NTILES 216        // ceil(8192/38)
#define NPROJ 29

#define WQ1_ELEMS (3*6*12*512)   // 110592
#define WQ2_ELEMS (6*2*512)      // 6144

typedef __bf16 bf16x8 __attribute__((ext_vector_type(8)));
typedef __bf16 bf16x4 __attribute__((ext_vector_type(4)));
typedef __bf16 bf16x2 __attribute__((ext_vector_type(2)));
typedef float  f32x4  __attribute__((ext_vector_type(4)));

// gelu via tanh-approx: gelu(v) = v * sigmoid(1.59577 v + 0.0713548 v^3)
__device__ __forceinline__ float gelu_fast(float v) {
    float vv = v * v;
    float u2 = v * fmaf(0.0713548162f, vv, 1.5957691216f);
    float t  = __expf(u2);
    float r  = __builtin_amdgcn_rcpf(t + 1.0f);
    return v - v * r;
}
__device__ __forceinline__ float softplus_f(float v) {
    float e = __expf(-fabsf(v));
    return fmaxf(v, 0.0f) + __logf(1.0f + e);
}

// Prepack pw_w (3x192x192) + w_proj (29x192 -> 32 rows) into MFMA A-frag bf16.
__global__ __launch_bounds__(256) void prepack_kernel(
    const float* __restrict__ pw_w, const float* __restrict__ w_proj,
    __bf16* __restrict__ wq, __bf16* __restrict__ wq2) {
    int idx = blockIdx.x * 256 + threadIdx.x;
    if (idx < WQ1_ELEMS) {
        int e    = idx & 7;
        int lane = (idx >> 3) & 63;
        int r    = idx >> 9;
        int mt   = r % 12;
        int ks   = (r / 12) % 6;
        int li   = r / 72;
        int o = 16 * mt + (lane & 15);
        int c = 32 * ks + 8 * (lane >> 4) + e;
        wq[idx] = (__bf16)pw_w[((size_t)li * CC + o) * CC + c];
    } else if (idx < WQ1_ELEMS + WQ2_ELEMS) {
        int i2   = idx - WQ1_ELEMS;
        int e    = i2 & 7;
        int lane = (i2 >> 3) & 63;
        int r    = i2 >> 9;          // 0..11  = ks*2 + pr
        int pr   = r % 2;
        int ks   = r / 2;
        int row  = 16 * pr + (lane & 15);
        int c    = 32 * ks + 8 * (lane >> 4) + e;
        wq2[i2] = (row < NPROJ) ? (__bf16)w_proj[(size_t)row * CC + c] : (__bf16)0.0f;
    }
}

__global__ __launch_bounds__(NTH, 4) void convflow_kernel(
    const float* __restrict__ x, const float* __restrict__ xmask,
    const float* __restrict__ w_pre, const float* __restrict__ b_pre,
    const float* __restrict__ sep_w, const float* __restrict__ sep_b,
    const __bf16* __restrict__ wq, const __bf16* __restrict__ wq2,
    const float* __restrict__ pw_b,
    const float* __restrict__ n1_g, const float* __restrict__ n1_b,
    const float* __restrict__ n2_g, const float* __restrict__ n2_b,
    const float* __restrict__ b_proj,
    float* __restrict__ out, float* __restrict__ logdet)
{
    extern __shared__ char smemraw[];
    __bf16* __restrict__ sh_t = (__bf16*)smemraw;          // [64][200] masked residual h
    __bf16* __restrict__ syt  = sh_t + EXT * LDC;          // [64][200] LN1/gelu out
    float*  __restrict__ sproj = (float*)syt;              // alias: [64][33]
    __bf16* __restrict__ spb  = syt + EXT * LDC;           // [192] bf16 per-layer params
    __bf16* __restrict__ sg2  = spb + CC;                  // [192]
    __bf16* __restrict__ sb2  = sg2 + CC;                  // [192]
    float*  __restrict__ fbase = (float*)(sb2 + CC);
    float*  __restrict__ sx0 = fbase;                      // [64]
    float*  __restrict__ sx1 = fbase + 64;
    float*  __restrict__ smk = fbase + 128;
    float2* __restrict__ sred = (float2*)(fbase + 192);    // [64][2]

    const int tid  = threadIdx.x;
    const int lane = tid & 63;
    const int wav  = tid >> 6;          // 0..7
    const int b    = blockIdx.x / NTILES;
    const int tile = blockIdx.x - b * NTILES;
    const int t0   = tile * INTR - HALO;

    // ---- stage 0: inputs ----
    for (int j = tid; j < EXT; j += NTH) {
        int t = t0 + j;
        bool ok = (t >= 0) && (t < TT);
        sx0[j] = ok ? x[b*2*TT + t]      : 0.0f;
        sx1[j] = ok ? x[b*2*TT + TT + t] : 0.0f;
        smk[j] = ok ? xmask[b*TT + t]    : 0.0f;
    }
    __syncthreads();

    // ---- pre-projection (masked, transposed bf16) + x0 output copy ----
    for (int e = tid; e < CC*EXT; e += NTH) {
        int c = e % CC;
        int j = e / CC;
        sh_t[j*LDC + c] = (__bf16)((sx0[j] * w_pre[c] + b_pre[c]) * smk[j]);
    }
    for (int q = tid; q < INTR; q += NTH) {
        int t = t0 + HALO + q;
        if (t < TT) out[b*2*TT + t] = sx0[HALO+q] * smk[HALO+q];
    }
    __syncthreads();

    const int g   = lane >> 4;
    const int c15 = lane & 15;
    const int cl  = lane & 31;          // conv: channels 6cl..6cl+5
    const int sub = lane >> 5;          // conv column selector (0/1)
    const int nt   = wav & 3;           // pointwise N-tile
    const int half = wav >> 2;          // pointwise M-half

    #pragma unroll
    for (int li = 0; li < 3; ++li) {
        constexpr int DILA[3] = {1, 3, 9};
        constexpr int JLOA[3] = {1, 4, 13};
        constexpr int JHIA[3] = {63, 60, 51};
        const int dil = DILA[li];
        const int jlo = JLOA[li], jhi = JHIA[li];

        // ---- stage per-layer params into LDS (bf16) ----
        for (int i = tid; i < CC; i += NTH) {
            spb[i] = (__bf16)pw_b[li*CC + i];
            sg2[i] = (__bf16)n2_g[li*CC + i];
            sb2[i] = (__bf16)n2_b[li*CC + i];
        }

        // ---- depthwise conv + LN1 + gelu -> syt (32 lanes x 2 cols, 6 ch/lane) ----
        {
            float k0[6], k1[6], k2[6], cb[6], g1[6], b1[6];
            #pragma unroll
            for (int k = 0; k < 6; ++k) {
                int c = 6*cl + k;
                k0[k] = sep_w[(li*3+0)*CC + c];
                k1[k] = sep_w[(li*3+1)*CC + c];
                k2[k] = sep_w[(li*3+2)*CC + c];
                cb[k] = sep_b[li*CC + c];
                g1[k] = n1_g[li*CC + c];
                b1[k] = n1_b[li*CC + c];
            }
            for (int j = jlo + 2*wav + sub; j < jhi; j += 16) {
                const bf16x2* r0 = (const bf16x2*)(sh_t + (j-dil)*LDC + 6*cl);
                const bf16x2* r1 = (const bf16x2*)(sh_t + j*LDC       + 6*cl);
                const bf16x2* r2 = (const bf16x2*)(sh_t + (j+dil)*LDC + 6*cl);
                bf16x2 t0v[3], t1v[3], t2v[3];
                #pragma unroll
                for (int p = 0; p < 3; ++p) { t0v[p] = r0[p]; t1v[p] = r1[p]; t2v[p] = r2[p]; }
                float a[6]; float s = 0.0f, ss = 0.0f;
                #pragma unroll
                for (int k = 0; k < 6; ++k) {
                    float v = k0[k]*(float)t0v[k>>1][k&1]
                            + k1[k]*(float)t1v[k>>1][k&1]
                            + k2[k]*(float)t2v[k>>1][k&1] + cb[k];
                    a[k] = v; s += v; ss += v*v;
                }
                #pragma unroll
                for (int mm = 1; mm < 32; mm <<= 1) {
                    s  += __shfl_xor(s,  mm, 64);
                    ss += __shfl_xor(ss, mm, 64);
                }
                float mean = s * (1.0f/CC);
                float var  = ss * (1.0f/CC) - mean*mean;
                float rstd = rsqrtf(var + 1e-5f);
                #pragma unroll
                for (int p = 0; p < 3; ++p) {
                    bf16x2 w;
                    w[0] = (__bf16)gelu_fast((a[2*p+0]-mean)*rstd*g1[2*p+0] + b1[2*p+0]);
                    w[1] = (__bf16)gelu_fast((a[2*p+1]-mean)*rstd*g1[2*p+1] + b1[2*p+1]);
                    *(bf16x2*)(syt + j*LDC + 6*cl + 2*p) = w;
                }
            }
        }
        __syncthreads();

        // ---- pointwise 192x192 MFMA: 8 jobs = (nt 0..3) x (M-half 0..1) ----
        {
            f32x4 acc[6];
            #pragma unroll
            for (int q = 0; q < 6; ++q) {
                bf16x4 pb = *(const bf16x4*)(spb + 16*(6*half+q) + 4*g);
                acc[q][0] = (float)pb[0]; acc[q][1] = (float)pb[1];
                acc[q][2] = (float)pb[2]; acc[q][3] = (float)pb[3];
            }
            const __bf16* wql = wq + (size_t)li * (6*12*512);
            #pragma unroll
            for (int ks = 0; ks < 6; ++ks) {
                bf16x8 bfrag = *(const bf16x8*)(syt + (16*nt + c15)*LDC + 32*ks + 8*g);
                const __bf16* ap = wql + (size_t)(ks*12 + 6*half)*512 + lane*8;
                #pragma unroll
                for (int q = 0; q < 6; ++q) {
                    bf16x8 afrag = *(const bf16x8*)(ap + (size_t)q*512);
                    acc[q] = __builtin_amdgcn_mfma_f32_16x16x32_bf16(afrag, bfrag, acc[q], 0, 0, 0);
                }
            }
            // partial LN2 stats over this half's 96 channels
            float s = 0.0f, ss = 0.0f;
            #pragma unroll
            for (int q = 0; q < 6; ++q) {
                #pragma unroll
                for (int e = 0; e < 4; ++e) { float z = acc[q][e]; s += z; ss += z*z; }
            }
            s  += __shfl_xor(s, 16, 64);  s  += __shfl_xor(s, 32, 64);
            ss += __shfl_xor(ss, 16, 64); ss += __shfl_xor(ss, 32, 64);
            if (lane < 16) sred[(16*nt + lane)*2 + half] = make_float2(s, ss);
            __syncthreads();
            const int col = 16*nt + c15;
            float2 e0 = sred[col*2], e1 = sred[col*2+1];
            float mean = (e0.x + e1.x) * (1.0f/CC);
            float var  = (e0.y + e1.y) * (1.0f/CC) - mean*mean;
            float rstd = rsqrtf(var + 1e-5f);
            float mj   = smk[col];
            #pragma unroll
            for (int q = 0; q < 6; ++q) {
                int mt = 6*half + q;
                bf16x4 gv = *(const bf16x4*)(sg2 + 16*mt + 4*g);
                bf16x4 bv = *(const bf16x4*)(sb2 + 16*mt + 4*g);
                bf16x4 hv = *(bf16x4*)(sh_t + (size_t)col*LDC + 16*mt + 4*g);
                hv[0] = (__bf16)((float)hv[0] + gelu_fast((acc[q][0]-mean)*rstd*(float)gv[0] + (float)bv[0])*mj);
                hv[1] = (__bf16)((float)hv[1] + gelu_fast((acc[q][1]-mean)*rstd*(float)gv[1] + (float)bv[1])*mj);
                hv[2] = (__bf16)((float)hv[2] + gelu_fast((acc[q][2]-mean)*rstd*(float)gv[2] + (float)bv[2])*mj);
                hv[3] = (__bf16)((float)hv[3] + gelu_fast((acc[q][3]-mean)*rstd*(float)gv[3] + (float)bv[3])*mj);
                *(bf16x4*)(sh_t + (size_t)col*LDC + 16*mt + 4*g) = hv;
            }
        }
        __syncthreads();
    }

    // ---- final projection: 8 jobs = (nt 0..3) x (row-half 0..1) ----
    {
        const int pr = half;
        f32x4 p0 = {0,0,0,0};
        #pragma unroll
        for (int ks = 0; ks < 6; ++ks) {
            bf16x8 bfrag = *(const bf16x8*)(sh_t + (16*nt + c15)*LDC + 32*ks + 8*g);
            bf16x8 a0 = *(const bf16x8*)(wq2 + (size_t)(ks*2 + pr)*512 + lane*8);
            p0 = __builtin_amdgcn_mfma_f32_16x16x32_bf16(a0, bfrag, p0, 0, 0, 0);
        }
        const int col = 16*nt + c15;
        if (col >= HALO && col < HALO + INTR) {
            float mj = smk[col];
            #pragma unroll
            for (int e = 0; e < 4; ++e) {
                int p = 16*pr + 4*g + e;
                if (p < NPROJ) sproj[col*33 + p] = (p0[e] + b_proj[p])*mj;
            }
        }
    }
    __syncthreads();

    // ---- rational-quadratic spline (wave 0) ----
    if (tid < 64) {
        int j = HALO + tid;
        int t = t0 + j;
        float ladm = 0.0f;
        if (tid < INTR && t < TT) {
            const float SCALE = 0.07216878364870323f;  // 1/sqrt(192)
            float mj = smk[j];
            float uw[10], uh[10];
            #pragma unroll
            for (int k = 0; k < 10; ++k) {
                uw[k] = sproj[j*33 + k]      * SCALE;
                uh[k] = sproj[j*33 + 10 + k] * SCALE;
            }
            float mxw = uw[0];
            #pragma unroll
            for (int k = 1; k < 10; ++k) mxw = fmaxf(mxw, uw[k]);
            float ew[10]; float sew = 0.0f;
            #pragma unroll
            for (int k = 0; k < 10; ++k) { ew[k] = __expf(uw[k]-mxw); sew += ew[k]; }
            float invw = 1.0f/sew;
            float cw[11]; cw[0] = -5.0f;
            float run = 0.0f;
            #pragma unroll
            for (int k = 0; k < 10; ++k) { run += 0.001f + 0.99f*ew[k]*invw; cw[k+1] = -5.0f + 10.0f*run; }
            cw[10] = 5.0f;
            float mxh = uh[0];
            #pragma unroll
            for (int k = 1; k < 10; ++k) mxh = fmaxf(mxh, uh[k]);
            float eh[10]; float seh = 0.0f;
            #pragma unroll
            for (int k = 0; k < 10; ++k) { eh[k] = __expf(uh[k]-mxh); seh += eh[k]; }
            float invh = 1.0f/seh;
            float ch[11]; ch[0] = -5.0f;
            run = 0.0f;
            #pragma unroll
            for (int k = 0; k < 10; ++k) { run += 0.001f + 0.99f*eh[k]*invh; ch[k+1] = -5.0f + 10.0f*run; }
            ch[10] = 5.0f;
            float dd[11];
            dd[0] = 1.0f;
            #pragma unroll
            for (int k = 0; k < 9; ++k) dd[k+1] = 0.001f + softplus_f(sproj[j*33 + 20 + k]);
            dd[10] = 1.0f;

            float xv = sx1[j];
            bool inside = (xv >= -5.0f) && (xv <= 5.0f);
            float xi = fminf(fmaxf(xv, -5.0f), 5.0f);
            int idx = 0;
            #pragma unroll
            for (int k = 1; k <= 9; ++k) idx = (xi >= cw[k]) ? k : idx;
            float in_cw=0, in_w=1, in_ch=0, in_h=1, in_d=1, d_p=1;
            #pragma unroll
            for (int k = 0; k < 10; ++k) {
                if (k == idx) {
                    in_cw = cw[k]; in_w = cw[k+1]-cw[k];
                    in_ch = ch[k]; in_h = ch[k+1]-ch[k];
                    in_d  = dd[k]; d_p  = dd[k+1];
                }
            }
            float delta = in_h/in_w;
            float th  = (xi - in_cw)/in_w;
            float th1 = th*(1.0f-th);
            float num = in_h*(delta*th*th + in_d*th1);
            float den = delta + (in_d + d_p - 2.0f*delta)*th1;
            float yv  = in_ch + num/den;
            float omt = 1.0f - th;
            float dnum = delta*delta*(d_p*th*th + 2.0f*delta*th1 + in_d*omt*omt);
            float lad = __logf(dnum) - 2.0f*__logf(den);
            if (!inside) { yv = xv; lad = 0.0f; }
            out[b*2*TT + TT + t] = yv*mj;
            ladm = lad*mj;
        }
        #pragma unroll
        for (int mm = 1; mm < 64; mm <<= 1) ladm += __shfl_xor(ladm, mm, 64);
        if (tid == 0) atomicAdd(&logdet[b], ladm);
    }
}

extern "C" void kernel_launch(void* const* d_in, const int* in_sizes, int n_in,
                              void* d_out, int out_size, void* d_ws, size_t ws_size,
                              hipStream_t stream) {
    const float* x      = (const float*)d_in[0];
    const float* xmask  = (const float*)d_in[1];
    const float* w_pre  = (const float*)d_in[2];
    const float* b_pre  = (const float*)d_in[3];
    const float* sep_w  = (const float*)d_in[4];
    const float* sep_b  = (const float*)d_in[5];
    const float* pw_w   = (const float*)d_in[6];
    const float* pw_b   = (const float*)d_in[7];
    const float* n1_g   = (const float*)d_in[8];
    const float* n1_b   = (const float*)d_in[9];
    const float* n2_g   = (const float*)d_in[10];
    const float* n2_b   = (const float*)d_in[11];
    const float* w_proj = (const float*)d_in[12];
    const float* b_proj = (const float*)d_in[13];
    float* out = (float*)d_out;
    float* logdet = out + (size_t)BATCH*2*TT;
    __bf16* wq  = (__bf16*)d_ws;
    __bf16* wq2 = wq + WQ1_ELEMS;

    hipMemsetAsync((void*)logdet, 0, BATCH*sizeof(float), stream);
    prepack_kernel<<<dim3((WQ1_ELEMS + WQ2_ELEMS + 255)/256), 256, 0, stream>>>(
        pw_w, w_proj, wq, wq2);

    // 51200 (2 planes) + 1152 (bf16 params) + 768 (sx) + 1024 (sred) = 54144 B
    // 54144*3 = 162432 <= 163840 -> 3 blocks/CU if VGPR <= 85
    size_t shbytes = (size_t)(2*EXT*LDC*2 + 3*CC*2 + 192*4 + 64*2*8);
    dim3 grid(BATCH*NTILES);
    convflow_kernel<<<grid, NTH, shbytes, stream>>>(
        x, xmask, w_pre, b_pre, sep_w, sep_b, wq, wq2, pw_b,
        n1_g, n1_b, n2_g, n2_b, b_proj, out, logdet);
}

// Round 8
// 256.768 us; speedup vs baseline: 1.1996x; 1.0025x over previous
//
#include <hip/hip_runtime.h>

#define CC    192
#define EXT   64
#define LDC   200         // bf16 row stride (400 B); cols 192..199 are the "tail" scratch
#define NTH   512         // 8 waves
#define HALO  13
#define INTR  38
#define TT    8192
#define BATCH 16
#define NTILES 216        // ceil(8192/38)
#define NPROJ 29

#define WQ1_ELEMS (3*6*12*512)   // 110592
#define WQ2_ELEMS (6*2*512)      // 6144

typedef __bf16 bf16x8 __attribute__((ext_vector_type(8)));
typedef __bf16 bf16x4 __attribute__((ext_vector_type(4)));
typedef __bf16 bf16x2 __attribute__((ext_vector_type(2)));
typedef float  f32x4  __attribute__((ext_vector_type(4)));

// gelu via tanh-approx: gelu(v) = v * sigmoid(1.59577 v + 0.0713548 v^3)
__device__ __forceinline__ float gelu_fast(float v) {
    float vv = v * v;
    float u2 = v * fmaf(0.0713548162f, vv, 1.5957691216f);
    float t  = __expf(u2);
    float r  = __builtin_amdgcn_rcpf(t + 1.0f);
    return v - v * r;
}
__device__ __forceinline__ float softplus_f(float v) {
    float e = __expf(-fabsf(v));
    return fmaxf(v, 0.0f) + __logf(1.0f + e);
}

// Prepack pw_w (3x192x192) + w_proj (29x192 -> 32 rows) into MFMA A-frag bf16.
__global__ __launch_bounds__(256) void prepack_kernel(
    const float* __restrict__ pw_w, const float* __restrict__ w_proj,
    __bf16* __restrict__ wq, __bf16* __restrict__ wq2) {
    int idx = blockIdx.x * 256 + threadIdx.x;
    if (idx < WQ1_ELEMS) {
        int e    = idx & 7;
        int lane = (idx >> 3) & 63;
        int r    = idx >> 9;
        int mt   = r % 12;
        int ks   = (r / 12) % 6;
        int li   = r / 72;
        int o = 16 * mt + (lane & 15);
        int c = 32 * ks + 8 * (lane >> 4) + e;
        wq[idx] = (__bf16)pw_w[((size_t)li * CC + o) * CC + c];
    } else if (idx < WQ1_ELEMS + WQ2_ELEMS) {
        int i2   = idx - WQ1_ELEMS;
        int e    = i2 & 7;
        int lane = (i2 >> 3) & 63;
        int r    = i2 >> 9;          // 0..11  = ks*2 + pr
        int pr   = r % 2;
        int ks   = r / 2;
        int row  = 16 * pr + (lane & 15);
        int c    = 32 * ks + 8 * (lane >> 4) + e;
        wq2[i2] = (row < NPROJ) ? (__bf16)w_proj[(size_t)row * CC + c] : (__bf16)0.0f;
    }
}

__global__ __launch_bounds__(NTH, 4) void convflow_kernel(
    const float* __restrict__ x, const float* __restrict__ xmask,
    const float* __restrict__ w_pre, const float* __restrict__ b_pre,
    const float* __restrict__ sep_w, const float* __restrict__ sep_b,
    const __bf16* __restrict__ wq, const __bf16* __restrict__ wq2,
    const float* __restrict__ pw_b,
    const float* __restrict__ n1_g, const float* __restrict__ n1_b,
    const float* __restrict__ n2_g, const float* __restrict__ n2_b,
    const float* __restrict__ b_proj,
    float* __restrict__ out, float* __restrict__ logdet)
{
    extern __shared__ char smemraw[];
    __bf16* __restrict__ sh_t = (__bf16*)smemraw;          // [64][200] masked residual h
    __bf16* __restrict__ syt  = sh_t + EXT * LDC;          // [64][200] LN1/gelu out
    float*  __restrict__ sproj = (float*)syt;              // alias: [64][33] (post-sred)
    __bf16* __restrict__ spb  = syt + EXT * LDC;           // [192] bf16 per-layer params
    __bf16* __restrict__ sg2  = spb + CC;                  // [192]
    __bf16* __restrict__ sb2  = sg2 + CC;                  // [192]

    // scalar scratch packed into dead per-row tails (cols 192..199 = 16 B/row):
    //   sh_t row j tail:  [0]=x0, [1]=x1, [2]=mask
    //   syt  row j tail:  float2 sred[2] (LN2 partial stats, halves 0/1)
#define SXROW(j) ((float*)(smemraw + (size_t)(j)*400 + 384))
#define SREDP(j) ((float2*)(smemraw + 25600 + (size_t)(j)*400 + 384))

    const int tid  = threadIdx.x;
    const int lane = tid & 63;
    const int wav  = tid >> 6;          // 0..7
    const int b    = blockIdx.x / NTILES;
    const int tile = blockIdx.x - b * NTILES;
    const int t0   = tile * INTR - HALO;

    // ---- stage 0: inputs into sh_t tails ----
    for (int j = tid; j < EXT; j += NTH) {
        int t = t0 + j;
        bool ok = (t >= 0) && (t < TT);
        float* sxr = SXROW(j);
        sxr[0] = ok ? x[b*2*TT + t]      : 0.0f;
        sxr[1] = ok ? x[b*2*TT + TT + t] : 0.0f;
        sxr[2] = ok ? xmask[b*TT + t]    : 0.0f;
    }
    __syncthreads();

    // ---- pre-projection (masked, transposed bf16) + x0 output copy ----
    for (int e = tid; e < CC*EXT; e += NTH) {
        int c = e % CC;
        int j = e / CC;
        const float* sxr = SXROW(j);
        sh_t[j*LDC + c] = (__bf16)((sxr[0] * w_pre[c] + b_pre[c]) * sxr[2]);
    }
    for (int q = tid; q < INTR; q += NTH) {
        int t = t0 + HALO + q;
        const float* sxr = SXROW(HALO+q);
        if (t < TT) out[b*2*TT + t] = sxr[0] * sxr[2];
    }
    __syncthreads();

    const int g   = lane >> 4;
    const int c15 = lane & 15;
    const int cl  = lane & 31;          // conv: channels 6cl..6cl+5
    const int sub = lane >> 5;          // conv column selector (0/1)
    const int nt   = wav & 3;           // pointwise N-tile
    const int half = wav >> 2;          // pointwise M-half

    #pragma unroll
    for (int li = 0; li < 3; ++li) {
        constexpr int DILA[3] = {1, 3, 9};
        constexpr int JLOA[3] = {1, 4, 13};
        constexpr int JHIA[3] = {63, 60, 51};
        const int dil = DILA[li];
        const int jlo = JLOA[li], jhi = JHIA[li];

        // ---- stage per-layer params into LDS (bf16) ----
        for (int i = tid; i < CC; i += NTH) {
            spb[i] = (__bf16)pw_b[li*CC + i];
            sg2[i] = (__bf16)n2_g[li*CC + i];
            sb2[i] = (__bf16)n2_b[li*CC + i];
        }

        // ---- depthwise conv + LN1 + gelu -> syt (32 lanes x 2 cols, 6 ch/lane) ----
        {
            float k0[6], k1[6], k2[6], cb[6], g1[6], b1[6];
            #pragma unroll
            for (int k = 0; k < 6; ++k) {
                int c = 6*cl + k;
                k0[k] = sep_w[(li*3+0)*CC + c];
                k1[k] = sep_w[(li*3+1)*CC + c];
                k2[k] = sep_w[(li*3+2)*CC + c];
                cb[k] = sep_b[li*CC + c];
                g1[k] = n1_g[li*CC + c];
                b1[k] = n1_b[li*CC + c];
            }
            for (int j = jlo + 2*wav + sub; j < jhi; j += 16) {
                float m0 = SXROW(j-dil)[2], m1 = SXROW(j)[2], m2 = SXROW(j+dil)[2];
                (void)m0; (void)m1; (void)m2;   // h pre-masked; masks folded already
                const bf16x2* r0 = (const bf16x2*)(sh_t + (j-dil)*LDC + 6*cl);
                const bf16x2* r1 = (const bf16x2*)(sh_t + j*LDC       + 6*cl);
                const bf16x2* r2 = (const bf16x2*)(sh_t + (j+dil)*LDC + 6*cl);
                bf16x2 t0v[3], t1v[3], t2v[3];
                #pragma unroll
                for (int p = 0; p < 3; ++p) { t0v[p] = r0[p]; t1v[p] = r1[p]; t2v[p] = r2[p]; }
                float a[6]; float s = 0.0f, ss = 0.0f;
                #pragma unroll
                for (int k = 0; k < 6; ++k) {
                    float v = k0[k]*(float)t0v[k>>1][k&1]
                            + k1[k]*(float)t1v[k>>1][k&1]
                            + k2[k]*(float)t2v[k>>1][k&1] + cb[k];
                    a[k] = v; s += v; ss += v*v;
                }
                #pragma unroll
                for (int mm = 1; mm < 32; mm <<= 1) {
                    s  += __shfl_xor(s,  mm, 64);
                    ss += __shfl_xor(ss, mm, 64);
                }
                float mean = s * (1.0f/CC);
                float var  = ss * (1.0f/CC) - mean*mean;
                float rstd = rsqrtf(var + 1e-5f);
                #pragma unroll
                for (int p = 0; p < 3; ++p) {
                    bf16x2 w;
                    w[0] = (__bf16)gelu_fast((a[2*p+0]-mean)*rstd*g1[2*p+0] + b1[2*p+0]);
                    w[1] = (__bf16)gelu_fast((a[2*p+1]-mean)*rstd*g1[2*p+1] + b1[2*p+1]);
                    *(bf16x2*)(syt + j*LDC + 6*cl + 2*p) = w;
                }
            }
        }
        __syncthreads();

        // ---- pointwise 192x192 MFMA: 8 jobs = (nt 0..3) x (M-half 0..1) ----
        {
            f32x4 acc[6];
            #pragma unroll
            for (int q = 0; q < 6; ++q) {
                bf16x4 pb = *(const bf16x4*)(spb + 16*(6*half+q) + 4*g);
                acc[q][0] = (float)pb[0]; acc[q][1] = (float)pb[1];
                acc[q][2] = (float)pb[2]; acc[q][3] = (float)pb[3];
            }
            const __bf16* wql = wq + (size_t)li * (6*12*512);
            #pragma unroll
            for (int ks = 0; ks < 6; ++ks) {
                bf16x8 bfrag = *(const bf16x8*)(syt + (16*nt + c15)*LDC + 32*ks + 8*g);
                const __bf16* ap = wql + (size_t)(ks*12 + 6*half)*512 + lane*8;
                #pragma unroll
                for (int q = 0; q < 6; ++q) {
                    bf16x8 afrag = *(const bf16x8*)(ap + (size_t)q*512);
                    acc[q] = __builtin_amdgcn_mfma_f32_16x16x32_bf16(afrag, bfrag, acc[q], 0, 0, 0);
                }
            }
            // partial LN2 stats over this half's 96 channels -> syt row tails
            float s = 0.0f, ss = 0.0f;
            #pragma unroll
            for (int q = 0; q < 6; ++q) {
                #pragma unroll
                for (int e = 0; e < 4; ++e) { float z = acc[q][e]; s += z; ss += z*z; }
            }
            s  += __shfl_xor(s, 16, 64);  s  += __shfl_xor(s, 32, 64);
            ss += __shfl_xor(ss, 16, 64); ss += __shfl_xor(ss, 32, 64);
            if (lane < 16) SREDP(16*nt + lane)[half] = make_float2(s, ss);
            __syncthreads();
            const int col = 16*nt + c15;
            float2 e0 = SREDP(col)[0], e1 = SREDP(col)[1];
            float mean = (e0.x + e1.x) * (1.0f/CC);
            float var  = (e0.y + e1.y) * (1.0f/CC) - mean*mean;
            float rstd = rsqrtf(var + 1e-5f);
            float mj   = SXROW(col)[2];
            #pragma unroll
            for (int q = 0; q < 6; ++q) {
                int mt = 6*half + q;
                bf16x4 gv = *(const bf16x4*)(sg2 + 16*mt + 4*g);
                bf16x4 bv = *(const bf16x4*)(sb2 + 16*mt + 4*g);
                bf16x4 hv = *(bf16x4*)(sh_t + (size_t)col*LDC + 16*mt + 4*g);
                hv[0] = (__bf16)((float)hv[0] + gelu_fast((acc[q][0]-mean)*rstd*(float)gv[0] + (float)bv[0])*mj);
                hv[1] = (__bf16)((float)hv[1] + gelu_fast((acc[q][1]-mean)*rstd*(float)gv[1] + (float)bv[1])*mj);
                hv[2] = (__bf16)((float)hv[2] + gelu_fast((acc[q][2]-mean)*rstd*(float)gv[2] + (float)bv[2])*mj);
                hv[3] = (__bf16)((float)hv[3] + gelu_fast((acc[q][3]-mean)*rstd*(float)gv[3] + (float)bv[3])*mj);
                *(bf16x4*)(sh_t + (size_t)col*LDC + 16*mt + 4*g) = hv;
            }
        }
        __syncthreads();
    }

    // ---- final projection: 8 jobs = (nt 0..3) x (row-half 0..1) ----
    {
        const int pr = half;
        f32x4 p0 = {0,0,0,0};
        #pragma unroll
        for (int ks = 0; ks < 6; ++ks) {
            bf16x8 bfrag = *(const bf16x8*)(sh_t + (16*nt + c15)*LDC + 32*ks + 8*g);
            bf16x8 a0 = *(const bf16x8*)(wq2 + (size_t)(ks*2 + pr)*512 + lane*8);
            p0 = __builtin_amdgcn_mfma_f32_16x16x32_bf16(a0, bfrag, p0, 0, 0, 0);
        }
        const int col = 16*nt + c15;
        if (col >= HALO && col < HALO + INTR) {
            float mj = SXROW(col)[2];
            #pragma unroll
            for (int e = 0; e < 4; ++e) {
                int p = 16*pr + 4*g + e;
                if (p < NPROJ) sproj[col*33 + p] = (p0[e] + b_proj[p])*mj;
            }
        }
    }
    __syncthreads();

    // ---- rational-quadratic spline (wave 0) ----
    if (tid < 64) {
        int j = HALO + tid;
        int t = t0 + j;
        float ladm = 0.0f;
        if (tid < INTR && t < TT) {
            const float SCALE = 0.07216878364870323f;  // 1/sqrt(192)
            float mj = SXROW(j)[2];
            float xv = SXROW(j)[1];
            float uw[10], uh[10];
            #pragma unroll
            for (int k = 0; k < 10; ++k) {
                uw[k] = sproj[j*33 + k]      * SCALE;
                uh[k] = sproj[j*33 + 10 + k] * SCALE;
            }
            float mxw = uw[0];
            #pragma unroll
            for (int k = 1; k < 10; ++k) mxw = fmaxf(mxw, uw[k]);
            float ew[10]; float sew = 0.0f;
            #pragma unroll
            for (int k = 0; k < 10; ++k) { ew[k] = __expf(uw[k]-mxw); sew += ew[k]; }
            float invw = 1.0f/sew;
            float cw[11]; cw[0] = -5.0f;
            float run = 0.0f;
            #pragma unroll
            for (int k = 0; k < 10; ++k) { run += 0.001f + 0.99f*ew[k]*invw; cw[k+1] = -5.0f + 10.0f*run; }
            cw[10] = 5.0f;
            float mxh = uh[0];
            #pragma unroll
            for (int k = 1; k < 10; ++k) mxh = fmaxf(mxh, uh[k]);
            float eh[10]; float seh = 0.0f;
            #pragma unroll
            for (int k = 0; k < 10; ++k) { eh[k] = __expf(uh[k]-mxh); seh += eh[k]; }
            float invh = 1.0f/seh;
            float ch[11]; ch[0] = -5.0f;
            run = 0.0f;
            #pragma unroll
            for (int k = 0; k < 10; ++k) { run += 0.001f + 0.99f*eh[k]*invh; ch[k+1] = -5.0f + 10.0f*run; }
            ch[10] = 5.0f;
            float dd[11];
            dd[0] = 1.0f;
            #pragma unroll
            for (int k = 0; k < 9; ++k) dd[k+1] = 0.001f + softplus_f(sproj[j*33 + 20 + k]);
            dd[10] = 1.0f;

            bool inside = (xv >= -5.0f) && (xv <= 5.0f);
            float xi = fminf(fmaxf(xv, -5.0f), 5.0f);
            int idx = 0;
            #pragma unroll
            for (int k = 1; k <= 9; ++k) idx = (xi >= cw[k]) ? k : idx;
            float in_cw=0, in_w=1, in_ch=0, in_h=1, in_d=1, d_p=1;
            #pragma unroll
            for (int k = 0; k < 10; ++k) {
                if (k == idx) {
                    in_cw = cw[k]; in_w = cw[k+1]-cw[k];
                    in_ch = ch[k]; in_h = ch[k+1]-ch[k];
                    in_d  = dd[k]; d_p  = dd[k+1];
                }
            }
            float delta = in_h/in_w;
            float th  = (xi - in_cw)/in_w;
            float th1 = th*(1.0f-th);
            float num = in_h*(delta*th*th + in_d*th1);
            float den = delta + (in_d + d_p - 2.0f*delta)*th1;
            float yv  = in_ch + num/den;
            float omt = 1.0f - th;
            float dnum = delta*delta*(d_p*th*th + 2.0f*delta*th1 + in_d*omt*omt);
            float lad = __logf(dnum) - 2.0f*__logf(den);
            if (!inside) { yv = xv; lad = 0.0f; }
            out[b*2*TT + TT + t] = yv*mj;
            ladm = lad*mj;
        }
        #pragma unroll
        for (int mm = 1; mm < 64; mm <<= 1) ladm += __shfl_xor(ladm, mm, 64);
        if (tid == 0) atomicAdd(&logdet[b], ladm);
    }
#undef SXROW
#undef SREDP
}

extern "C" void kernel_launch(void* const* d_in, const int* in_sizes, int n_in,
                              void* d_out, int out_size, void* d_ws, size_t ws_size,
                              hipStream_t stream) {
    const float* x      = (const float*)d_in[0];
    const float* xmask  = (const float*)d_in[1];
    const float* w_pre  = (const float*)d_in[2];
    const float* b_pre  = (const float*)d_in[3];
    const float* sep_w  = (const float*)d_in[4];
    const float* sep_b  = (const float*)d_in[5];
    const float* pw_w   = (const float*)d_in[6];
    const float* pw_b   = (const float*)d_in[7];
    const float* n1_g   = (const float*)d_in[8];
    const float* n1_b   = (const float*)d_in[9];
    const float* n2_g   = (const float*)d_in[10];
    const float* n2_b   = (const float*)d_in[11];
    const float* w_proj = (const float*)d_in[12];
    const float* b_proj = (const float*)d_in[13];
    float* out = (float*)d_out;
    float* logdet = out + (size_t)BATCH*2*TT;
    __bf16* wq  = (__bf16*)d_ws;
    __bf16* wq2 = wq + WQ1_ELEMS;

    hipMemsetAsync((void*)logdet, 0, BATCH*sizeof(float), stream);
    prepack_kernel<<<dim3((WQ1_ELEMS + WQ2_ELEMS + 255)/256), 256, 0, stream>>>(
        pw_w, w_proj, wq, wq2);

    // 51200 (2 planes, scalars in row tails) + 1152 (bf16 params) = 52352 B
    // <= 52992 (R5's empirically-3-block size) -> 3 blocks/CU
    size_t shbytes = (size_t)(2*EXT*LDC*2 + 3*CC*2);
    dim3 grid(BATCH*NTILES);
    convflow_kernel<<<grid, NTH, shbytes, stream>>>(
        x, xmask, w_pre, b_pre, sep_w, sep_b, wq, wq2, pw_b,
        n1_g, n1_b, n2_g, n2_b, b_proj, out, logdet);
}